// Round 1
// 543.406 us; speedup vs baseline: 1.0571x; 1.0571x over previous
//
#include <hip/hip_runtime.h>
#include <stdint.h>

#define D_MODEL 1024
#define NHEAD 16
#define DH 64
#define DFF 4096
#define BATCH 4
#define SEQ 2048
#define MTOT (BATCH*SEQ)   // 8192 rows total

// Q pre-scale folds 1/sqrt(Dh) AND log2(e) so softmax is a bare v_exp_f32 (exp2):
//   s' = s * log2e;  p = exp2(min(s', 10*log2e)) = exp(min(s,10))
#define QSCALE 0.18033688011112043f   // 0.125 * log2(e)
#define CLIP2  14.426950408889634f    // 10 * log2(e)

typedef short short8 __attribute__((ext_vector_type(8)));
typedef float f32x4 __attribute__((ext_vector_type(4)));
typedef unsigned int uint;

__device__ inline unsigned short f2bf(float f) {
  union { float f; unsigned u; } v; v.f = f;
  unsigned r = v.u + 0x7fffu + ((v.u >> 16) & 1u);
  return (unsigned short)(r >> 16);
}
__device__ inline float bf2f(unsigned short b) {
  union { unsigned u; float f; } v; v.u = ((unsigned)b) << 16;
  return v.f;
}
// truncation-pack two floats to bf16 pair in one dword: [lo | hi<<16]
__device__ inline unsigned pack_trunc(float lo, float hi) {
  union { float f; unsigned u; } a, b; a.f = lo; b.f = hi;
  return __builtin_amdgcn_perm(b.u, a.u, 0x07060302u);
}
// async 16B global -> LDS (wave-uniform base + lane*16 contract)
__device__ __forceinline__ void async16(const unsigned short* g, unsigned short* l) {
  __builtin_amdgcn_global_load_lds(
      (const __attribute__((address_space(1))) unsigned int*)g,
      (__attribute__((address_space(3))) unsigned int*)l, 16, 0, 0);
}

// ---------------- cast x -> bf16 ----------------
__global__ void cast_kernel(const float* __restrict__ in, unsigned short* __restrict__ out, int n4) {
  int i = blockIdx.x * blockDim.x + threadIdx.x;
  if (i < n4) {
    float4 v = ((const float4*)in)[i];
    ushort4 o;
    o.x = f2bf(v.x); o.y = f2bf(v.y); o.z = f2bf(v.z); o.w = f2bf(v.w);
    ((ushort4*)out)[i] = o;
  }
}

// ------------- ALL weight transposes, ONE launch, EXACT flat grid (12288 blocks) -------------
// tiles: [0,4096): wq|wk|wv|wo (1024 each); [4096,8192): w1; [8192,12288): w2
__global__ void transpose_weights_kernel(
    const float* __restrict__ wq, const float* __restrict__ wk,
    const float* __restrict__ wv, const float* __restrict__ wo,
    const float* __restrict__ w1, const float* __restrict__ w2,
    unsigned short* __restrict__ wqkvT, unsigned short* __restrict__ woT,
    unsigned short* __restrict__ w1T, unsigned short* __restrict__ w2T) {
  __shared__ unsigned short tile[32][33];
  const int id = blockIdx.x;
  const float* in; unsigned short* out; int K, N, n0, k0; float scale = 1.0f;
  if (id < 4096) {
    const int wi = id >> 10, t = id & 1023;
    switch (wi) {
      case 0:  in = wq; out = wqkvT;           scale = QSCALE; break;
      case 1:  in = wk; out = wqkvT + 1048576; break;
      case 2:  in = wv; out = wqkvT + 2097152; break;
      default: in = wo; out = woT;             break;
    }
    K = 1024; N = 1024; n0 = (t & 31) * 32; k0 = (t >> 5) * 32;
  } else if (id < 8192) {
    const int t = id - 4096;
    in = w1; out = w1T; K = 1024; N = 4096; n0 = (t & 127) * 32; k0 = (t >> 7) * 32;
  } else {
    const int t = id - 8192;
    in = w2; out = w2T; K = 4096; N = 1024; n0 = (t & 31) * 32; k0 = (t >> 5) * 32;
  }
  const int tx = threadIdx.x & 31, ty = threadIdx.x >> 5;  // 32 x 8
#pragma unroll
  for (int j = 0; j < 32; j += 8)
    tile[ty + j][tx] = f2bf(in[(size_t)(k0 + ty + j) * N + n0 + tx] * scale);
  __syncthreads();
#pragma unroll
  for (int j = 0; j < 32; j += 8)
    out[(size_t)(n0 + ty + j) * K + k0 + tx] = tile[tx][ty + j];
}

// ------------- concat + scale biases into [3072] -------------
__global__ void bias_concat_kernel(const float* __restrict__ bq, const float* __restrict__ bk,
                                   const float* __restrict__ bv, float* __restrict__ o) {
  int i = blockIdx.x * 256 + threadIdx.x;
  if (i < 3 * D_MODEL) {
    float v = (i < D_MODEL) ? bq[i] * QSCALE
            : (i < 2 * D_MODEL) ? bk[i - D_MODEL] : bv[i - 2 * D_MODEL];
    o[i] = v;
  }
}

// ------------- transpose V (from qkv cols 2048..3071) into Vt_g[bh][dh][kv] -------------
__global__ void transpose_v_kernel(const unsigned short* __restrict__ QKV,
                                   unsigned short* __restrict__ Vt) {
  __shared__ unsigned short tile[32][33];
  int bh = blockIdx.z, b = bh >> 4, h = bh & 15;
  int kv0 = blockIdx.x * 32, dh0 = blockIdx.y * 32;
  int tx = threadIdx.x & 31, ty = threadIdx.x >> 5;  // 32 x 8
#pragma unroll
  for (int j = 0; j < 32; j += 8)
    tile[ty + j][tx] = QKV[(size_t)(b * SEQ + kv0 + ty + j) * 3072 + 2048 + h * DH + dh0 + tx];
  __syncthreads();
#pragma unroll
  for (int j = 0; j < 32; j += 8)
    Vt[(size_t)(bh * DH + dh0 + ty + j) * SEQ + kv0 + tx] = tile[tx][ty + j];
}

// ------------- GEMM (legacy 128x128, m97-structure): used only for out-proj (N=1024) -------------
template<int RELU, int OUT_BF16, int KSPLIT, int BIAS>
__global__ __launch_bounds__(256, 4) void gemm_bt_kernel(
    const unsigned short* __restrict__ A,
    const unsigned short* __restrict__ Bt,
    const float* __restrict__ bias,
    void* __restrict__ Cout,
    int M, int N, int K) {
  __shared__ __align__(16) unsigned short As[128][32];
  __shared__ __align__(16) unsigned short Bs[128][32];
  const int GX = N >> 7;                    // n-tiles
  const int xcd = blockIdx.x & 7;
  int li = blockIdx.x >> 3;
  int kh = 0;
  if (KSPLIT == 2) { kh = li & 1; li >>= 1; }
  const int im = xcd * 8 + li / GX;         // m-tile (8 per XCD band, M=8192 always)
  const int in_ = li % GX;                  // n-tile, fast-varying within band
  const int m0 = im * 128, n0 = in_ * 128;
  const int tid = threadIdx.x;
  const int wave = tid >> 6, lane = tid & 63;
  const int wm = (wave >> 1) * 64, wn = (wave & 1) * 64;
  const int lm = lane & 15, lq = lane >> 4, lk = (lane >> 4) * 8;
  const int sr = tid >> 2;          // staging row 0..63 (+64 on 2nd round)
  const int sc = (tid & 3) * 8;     // staging col {0,8,16,24}
  f32x4 acc[4][4] = {};

  const int kbeg = (KSPLIT == 2) ? kh * (K >> 1) : 0;
  const int kend = (KSPLIT == 2) ? kbeg + (K >> 1) : K;
  for (int k0 = kbeg; k0 < kend; k0 += 32) {
    __syncthreads();
#pragma unroll
    for (int s = 0; s < 2; s++) {
      int row = sr + s * 64;
      async16(A  + (size_t)(m0 + row) * K + k0 + sc, &As[0][0] + row * 32 + sc);
      async16(Bt + (size_t)(n0 + row) * K + k0 + sc, &Bs[0][0] + row * 32 + sc);
    }
    __syncthreads();
    short8 af[4], bfr[4];
#pragma unroll
    for (int t = 0; t < 4; t++) {
      af[t]  = *(const short8*)(&As[wm + t * 16 + lm][lk]);
      bfr[t] = *(const short8*)(&Bs[wn + t * 16 + lm][lk]);
    }
#pragma unroll
    for (int mt = 0; mt < 4; mt++)
#pragma unroll
      for (int nt = 0; nt < 4; nt++)
        acc[mt][nt] = __builtin_amdgcn_mfma_f32_16x16x32_bf16(af[mt], bfr[nt], acc[mt][nt], 0, 0, 0);
  }
  // epilogue: C/D layout col=lane&15, row=(lane>>4)*4+r
  unsigned short* Cb = (unsigned short*)Cout + (KSPLIT == 2 ? (size_t)kh * M * N : 0);
#pragma unroll
  for (int nt = 0; nt < 4; nt++) {
    int col = n0 + wn + nt * 16 + lm;
    float bv = BIAS ? bias[col] : 0.0f;
#pragma unroll
    for (int mt = 0; mt < 4; mt++) {
#pragma unroll
      for (int r = 0; r < 4; r++) {
        int row = m0 + wm + mt * 16 + lq * 4 + r;
        float v = acc[mt][nt][r] + bv;
        if (RELU) v = fmaxf(v, 0.0f);
        if (OUT_BF16) Cb[(size_t)row * N + col] = f2bf(v);
        else          ((float*)Cout)[(size_t)row * N + col] = v;
      }
    }
  }
}

// ------------- GEMM 256x256, 8-phase counted-vmcnt schedule (T2+T3+T4+T5) -------------
// 512 threads = 8 waves (2 m x 4 n), per-wave C = 128x64 (acc[8][4]).
// LDS: double-buffered A[256][64]+B[256][64] bf16 = 128 KiB -> 1 block/CU, 2 waves/SIMD.
// Swizzle: 16B slot s of row r holds logical slot s^(r&7); applied on the GLOBAL source
// of global_load_lds (linear LDS dest, wave-uniform contract) and on the ds_read side.
// Per K-tile: 4 phases x 16 MFMA, raw s_barrier pairs, setprio(1) around MFMA cluster.
// Staging of K-tile t+2 spread 2 bands/phase in WAR-safe order (band staged only after
// the barrier sealing its last read); ONE s_waitcnt vmcnt(6) per K-tile (never 0 in
// steady state; vmcnt(0) only for the last 2 tail iterations).
//   band layout per tile: A0..A3 / B0..B3 = 64-row bands; 1 global_load_lds per thread per band.
//   read plan:  ph0: A m-half0 (8x b128) + B n-half0 (4x)  -> MFMA (m0,n0)
//               ph1: B n-half1 (4x)                        -> MFMA (m0,n1)
//               ph2: A m-half1 (8x, overwrite af)          -> MFMA (m1,n1)
//               ph3: none (bf held in regs)                -> MFMA (m1,n0)
//   stage plan: ph0: B2,B3(t+1)->nxt | ph1: A0,A2(t+2)->cur | ph2: B0,B1(t+2)->cur
//               ph3: A1,A3(t+2)->cur, then vmcnt(6)
#define MFMA_Q(mh, nh)                                                                     \
  _Pragma("unroll")                                                                        \
  for (int ks = 0; ks < 2; ks++) {                                                         \
    _Pragma("unroll")                                                                      \
    for (int i = 0; i < 4; i++) {                                                          \
      _Pragma("unroll")                                                                    \
      for (int nn = 0; nn < 2; nn++) {                                                     \
        acc[(mh)*4 + i][(nh)*2 + nn] = __builtin_amdgcn_mfma_f32_16x16x32_bf16(            \
            af[i][ks], bf[(nh)*2 + nn][ks], acc[(mh)*4 + i][(nh)*2 + nn], 0, 0, 0);        \
      }                                                                                    \
    }                                                                                      \
  }

template<int RELU, int OUT_BF16, int KSPLIT, int BIAS>
__global__ __launch_bounds__(512, 2) void gemm256_bt_kernel(
    const unsigned short* __restrict__ A,
    const unsigned short* __restrict__ Bt,
    const float* __restrict__ bias,
    void* __restrict__ Cout,
    int M, int N, int K) {
  __shared__ __align__(16) unsigned short lds[65536];   // 128 KiB: [buf][A 16384 | B 16384]

  // XCD-compact bijective swizzle (grid always a multiple of 8)
  const int nwg = gridDim.x;
  int nid = (blockIdx.x & 7) * (nwg >> 3) + (blockIdx.x >> 3);
  int kh = 0;
  if (KSPLIT == 2) { kh = nid & 1; nid >>= 1; }
  const int GX = N >> 8;
  const int im = nid / GX, in_ = nid % GX;
  const int m0 = im * 256, n0 = in_ * 256;

  const int tid = threadIdx.x;
  const int lane = tid & 63, wave = tid >> 6;
  const int wm = (wave >> 2) * 128, wn = (wave & 3) * 64;
  const int lm = lane & 15, lg = lane >> 4;
  const int rot = lm & 7;
  const int aoff0 = ((lg) ^ rot) << 3;        // elem offset of 16B slot, k-slice 0
  const int aoff1 = ((4 + lg) ^ rot) << 3;    // k-slice 1
  const int arow = (wm + lm) << 6;            // A frag row base (elements)
  const int brow = (wn + lm) << 6;            // B frag row base

  const int kbeg = (KSPLIT == 2) ? kh * (K >> 1) : 0;
  const int nk = ((KSPLIT == 2) ? (K >> 1) : K) >> 6;   // #K-tiles (>=2 for all uses)

  // staging: thread tid covers row rb=tid>>3 of a 64-row band, phys 16B slot tid&7;
  // global source column pre-swizzled so linear LDS dest yields swizzled layout.
  const int rb = tid >> 3;
  const int gcol = (((tid & 7) ^ (rb & 7)) << 3);
  const unsigned short* gA = A  + (size_t)(m0 + rb) * K + kbeg + gcol;
  const unsigned short* gB = Bt + (size_t)(n0 + rb) * K + kbeg + gcol;

  auto stage = [&](const unsigned short* g, int b, int st, unsigned short* seg) {
    async16(g + (size_t)b * 64 * K + (size_t)st * 64, seg + b * 4096 + tid * 8);
  };

  f32x4 acc[8][4] = {};

  // ---- prologue: K0 full (8 bands) + K1 first 6 bands; seal K0 with vmcnt(6) ----
  {
    unsigned short* A0s = lds;
    unsigned short* B0s = lds + 16384;
    unsigned short* A1s = lds + 32768;
    unsigned short* B1s = lds + 49152;
    stage(gA, 0, 0, A0s); stage(gA, 2, 0, A0s);
    stage(gB, 0, 0, B0s); stage(gB, 1, 0, B0s);
    stage(gA, 1, 0, A0s); stage(gA, 3, 0, A0s);
    stage(gB, 2, 0, B0s); stage(gB, 3, 0, B0s);
    stage(gA, 0, 1, A1s); stage(gA, 2, 1, A1s);
    stage(gB, 0, 1, B1s); stage(gB, 1, 1, B1s);
    stage(gA, 1, 1, A1s); stage(gA, 3, 1, A1s);
    __builtin_amdgcn_s_waitcnt(0x0F76);   // vmcnt(6): K0 landed, K1's 6 in flight
    __builtin_amdgcn_s_barrier();
  }

  for (int t = 0; t < nk; ++t) {
    const int cur = t & 1;
    unsigned short* LA = lds + (cur << 15);
    unsigned short* LB = LA + 16384;
    unsigned short* NA = lds + ((cur ^ 1) << 15);
    unsigned short* NB = NA + 16384;
    short8 af[4][2], bf[4][2];

    // ---------- phase 0: (m-half0, n-half0) ----------
    if (t + 1 < nk) { stage(gB, 2, t + 1, NB); stage(gB, 3, t + 1, NB); }
#pragma unroll
    for (int i = 0; i < 4; i++) {
      af[i][0] = *(const short8*)(LA + arow + i * 1024 + aoff0);
      af[i][1] = *(const short8*)(LA + arow + i * 1024 + aoff1);
    }
#pragma unroll
    for (int n = 0; n < 2; n++) {
      bf[n][0] = *(const short8*)(LB + brow + n * 1024 + aoff0);
      bf[n][1] = *(const short8*)(LB + brow + n * 1024 + aoff1);
    }
    __builtin_amdgcn_s_barrier();
    __builtin_amdgcn_s_setprio(1);
    MFMA_Q(0, 0);
    __builtin_amdgcn_s_setprio(0);
    __builtin_amdgcn_s_barrier();

    // ---------- phase 1: (m-half0, n-half1) ----------
    if (t + 2 < nk) { stage(gA, 0, t + 2, LA); stage(gA, 2, t + 2, LA); }
#pragma unroll
    for (int n = 2; n < 4; n++) {
      bf[n][0] = *(const short8*)(LB + brow + n * 1024 + aoff0);
      bf[n][1] = *(const short8*)(LB + brow + n * 1024 + aoff1);
    }
    __builtin_amdgcn_s_barrier();
    __builtin_amdgcn_s_setprio(1);
    MFMA_Q(0, 1);
    __builtin_amdgcn_s_setprio(0);
    __builtin_amdgcn_s_barrier();

    // ---------- phase 2: (m-half1, n-half1) ----------
    if (t + 2 < nk) { stage(gB, 0, t + 2, LB); stage(gB, 1, t + 2, LB); }
#pragma unroll
    for (int i = 0; i < 4; i++) {
      af[i][0] = *(const short8*)(LA + arow + 4096 + i * 1024 + aoff0);
      af[i][1] = *(const short8*)(LA + arow + 4096 + i * 1024 + aoff1);
    }
    __builtin_amdgcn_s_barrier();
    __builtin_amdgcn_s_setprio(1);
    MFMA_Q(1, 1);
    __builtin_amdgcn_s_setprio(0);
    __builtin_amdgcn_s_barrier();

    // ---------- phase 3: (m-half1, n-half0); seal next K-tile ----------
    if (t + 2 < nk) {
      stage(gA, 1, t + 2, LA); stage(gA, 3, t + 2, LA);
      __builtin_amdgcn_s_waitcnt(0x0F76);   // vmcnt(6): K-tile t+1 fully landed
    } else {
      __builtin_amdgcn_s_waitcnt(0x0F70);   // tail: vmcnt(0)
    }
    __builtin_amdgcn_s_barrier();
    __builtin_amdgcn_s_setprio(1);
    MFMA_Q(1, 0);
    __builtin_amdgcn_s_setprio(0);
    __builtin_amdgcn_s_barrier();
  }

  // ---- epilogue: C/D layout col=lane&15, row=(lane>>4)*4+r ----
  unsigned short* Cb = (unsigned short*)Cout + (KSPLIT == 2 ? (size_t)kh * M * N : 0);
#pragma unroll
  for (int nt = 0; nt < 4; nt++) {
    int col = n0 + wn + nt * 16 + lm;
    float bv = BIAS ? bias[col] : 0.0f;
#pragma unroll
    for (int mf = 0; mf < 8; mf++) {
#pragma unroll
      for (int r = 0; r < 4; r++) {
        int row = m0 + wm + mf * 16 + lg * 4 + r;
        float v = acc[mf][nt][r] + bv;
        if (RELU) v = fmaxf(v, 0.0f);
        if (OUT_BF16) Cb[(size_t)row * N + col] = f2bf(v);
        else          ((float*)Cout)[(size_t)row * N + col] = v;
      }
    }
  }
}

// ------------- attention: 128 q/block, 32 q/wave, 4 blocks/CU, reg-prefetch K/V -------------
// S^T = K*Q^T; p = exp2(min(s',CLIP2)) via native v_exp_f32; lower clip dropped
// (negligible vs rowsum); shift cancels in normalization. Rowsum via MFMA vs all-ones.
// Per-wave Ps roundtrip (lgkm wait only). LDS XOR swizzle phys_col = col ^ ((row&7)*8).
__global__ __launch_bounds__(256, 4) void attn_kernel(
    const unsigned short* __restrict__ QKV,   // [8192][3072]: q|k|v
    const unsigned short* __restrict__ Vt_g,  // [64 bh][64 dh][2048 kv]
    unsigned short* __restrict__ ctx) {       // [8192][1024]
  __shared__ __align__(16) unsigned short Ks[64 * 64];       // [kv][dh] swizzled
  __shared__ __align__(16) unsigned short Vs[64 * 64];       // [dh][kv] swizzled
  __shared__ __align__(16) unsigned short Ps[4 * 32 * 64];   // per-wave [q][kv] swizzled
  const int bh = blockIdx.x, b = bh >> 4, h = bh & 15;
  const int q0 = blockIdx.y * 128;
  const int tid = threadIdx.x, wave = tid >> 6, lane = tid & 63;
  const int lm = lane & 15, lq = lane >> 4;
  const int srow = tid >> 3, scol = (tid & 7) * 8;           // srow 0..31
  const int rot = (lm & 7) * 8;

  short8 qf[2][2];
#pragma unroll
  for (int ntq = 0; ntq < 2; ntq++) {
    const unsigned short* qp =
        QKV + (size_t)(b * SEQ + q0 + wave * 32 + ntq * 16 + lm) * 3072 + h * DH;
#pragma unroll
    for (int sl = 0; sl < 2; sl++) qf[ntq][sl] = *(const short8*)(qp + sl * 32 + lq * 8);
  }
  const short8 ones = {0x3F80, 0x3F80, 0x3F80, 0x3F80, 0x3F80, 0x3F80, 0x3F80, 0x3F80};
  f32x4 oacc[2][4] = {};
  f32x4 lsum[2] = {};

  const int sdst = srow * 64 + (scol ^ ((srow & 7) * 8));   // rows 0..31; +2048 for 32..63
  const unsigned short* kg = QKV + (size_t)(b * SEQ) * 3072 + D_MODEL + h * DH + scol;
  const unsigned short* vg = Vt_g + (size_t)(bh * DH + srow) * SEQ + scol;

  // prefetch tile 0
  uint4 kr0 = *(const uint4*)(kg + (size_t)srow * 3072);
  uint4 kr1 = *(const uint4*)(kg + (size_t)(srow + 32) * 3072);
  uint4 vr0 = *(const uint4*)(vg);
  uint4 vr1 = *(const uint4*)(vg + 32 * SEQ);

  for (int it = 0; it < SEQ / 64; it++) {
    *(uint4*)(Ks + sdst)        = kr0;
    *(uint4*)(Ks + sdst + 2048) = kr1;
    *(uint4*)(Vs + sdst)        = vr0;
    *(uint4*)(Vs + sdst + 2048) = vr1;
    __syncthreads();
    if (it + 1 < SEQ / 64) {   // prefetch next tile; overlaps the whole compute phase
      const int kvn = (it + 1) * 64;
      kr0 = *(const uint4*)(kg + (size_t)(kvn + srow) * 3072);
      kr1 = *(const uint4*)(kg + (size_t)(kvn + srow + 32) * 3072);
      vr0 = *(const uint4*)(vg + kvn);
      vr1 = *(const uint4*)(vg + 32 * SEQ + kvn);
    }

    // S^T = K * Q^T ; p = exp2(min(s',CLIP2)); truncation-pack to per-wave Ps
#pragma unroll
    for (int mt = 0; mt < 4; mt++) {
      const unsigned short* krow = Ks + (mt * 16 + lm) * 64;
      short8 kf0 = *(const short8*)(krow + ((lq * 8) ^ rot));
      short8 kf1 = *(const short8*)(krow + ((32 + lq * 8) ^ rot));
#pragma unroll
      for (int ntq = 0; ntq < 2; ntq++) {
        f32x4 sa = {0.f, 0.f, 0.f, 0.f};
        sa = __builtin_amdgcn_mfma_f32_16x16x32_bf16(kf0, qf[ntq][0], sa, 0, 0, 0);
        sa = __builtin_amdgcn_mfma_f32_16x16x32_bf16(kf1, qf[ntq][1], sa, 0, 0, 0);
        float p0 = exp2f(fminf(sa[0], CLIP2));
        float p1 = exp2f(fminf(sa[1], CLIP2));
        float p2 = exp2f(fminf(sa[2], CLIP2));
        float p3 = exp2f(fminf(sa[3], CLIP2));
        uint2 d;
        d.x = pack_trunc(p0, p1);
        d.y = pack_trunc(p2, p3);
        *(uint2*)(Ps + wave * 2048 + (ntq * 16 + lm) * 64 + ((mt * 16 + lq * 4) ^ rot)) = d;
      }
    }
    // wave-local LDS RAW: wait lgkmcnt(0) only (vmcnt=63, expcnt=7 -> 0xC07F)
    __builtin_amdgcn_s_waitcnt(0xC07F);
    short8 pf[2][2];
#pragma unroll
    for (int mq = 0; mq < 2; mq++)
#pragma unroll
      for (int sl = 0; sl < 2; sl++)
        pf[mq][sl] = *(const short8*)(Ps + wave * 2048 + (mq * 16 + lm) * 64 + ((sl * 32 + lq * 8) ^ rot));
#pragma unroll
    for (int nt = 0; nt < 4; nt++) {
      const unsigned short* vrow = Vs + (nt * 16 + lm) * 64;
      short8 vf0 = *(const short8*)(vrow + ((lq * 8) ^ rot));
      short8 vf1 = *(const short8*)(vrow + ((32 + lq * 8) ^ rot));
#pragma unroll
      for (int mq = 0; mq < 2; mq++) {
        oacc[mq][nt] = __builtin_amdgcn_mfma_f32_16x16x32_bf16(pf[mq][0], vf0, oacc[mq][nt], 0, 0, 0);
        oacc[mq][nt] = __builtin_amdgcn_mfma_f32_16x16x32_bf16(pf[mq][1], vf1, oacc[mq][nt], 0, 0, 0);
      }
    }
#pragma unroll
    for (int mq = 0; mq < 2; mq++) {
      lsum[mq] = __builtin_amdgcn_mfma_f32_16x16x32_bf16(pf[mq][0], ones, lsum[mq], 0, 0, 0);
      lsum[mq] = __builtin_amdgcn_mfma_f32_16x16x32_bf16(pf[mq][1], ones, lsum[mq], 0, 0, 0);
    }
    __syncthreads();   // all waves done reading Ks/Vs before next staging write
  }

#pragma unroll
  for (int mq = 0; mq < 2; mq++) {
    float linv[4];
#pragma unroll
    for (int r = 0; r < 4; r++) linv[r] = 1.0f / lsum[mq][r];
    const size_t rowbase =
        (size_t)(b * SEQ + q0 + wave * 32 + mq * 16 + lq * 4) * D_MODEL + h * DH;
#pragma unroll
    for (int nt = 0; nt < 4; nt++) {
#pragma unroll
      for (int r = 0; r < 4; r++) {
        ctx[rowbase + (size_t)r * D_MODEL + nt * 16 + lm] = f2bf(oacc[mq][nt][r] * linv[r]);
      }
    }
  }
}

// ------------- residual + layernorm -------------
// THREE=1: out = LN(A + bf16(B1) + bf16(B2) + cbias)  (split-K partial merge + bias)
template<int B_BF16, int WRITE_BF16, int THREE>
__global__ void ln_kernel(const float* __restrict__ A, const void* __restrict__ Bv,
                          const void* __restrict__ B2v, const float* __restrict__ cbias,
                          const float* __restrict__ gamma, const float* __restrict__ beta,
                          float* __restrict__ outf, unsigned short* __restrict__ outb) {
  const int row = blockIdx.x;
  const int tid = threadIdx.x;
  const size_t base = (size_t)row * D_MODEL + tid * 4;
  float4 xa = *(const float4*)(A + base);
  float4 xb;
  if (B_BF16) {
    ushort4 u = *(const ushort4*)((const unsigned short*)Bv + base);
    xb.x = bf2f(u.x); xb.y = bf2f(u.y); xb.z = bf2f(u.z); xb.w = bf2f(u.w);
  } else {
    xb = *(const float4*)((const float*)Bv + base);
  }
  if (THREE) {
    ushort4 u2 = *(const ushort4*)((const unsigned short*)B2v + base);
    float4 cb = *(const float4*)(cbias + tid * 4);
    xb.x += bf2f(u2.x) + cb.x; xb.y += bf2f(u2.y) + cb.y;
    xb.z += bf2f(u2.z) + cb.z; xb.w += bf2f(u2.w) + cb.w;
  }
  float v0 = xa.x + xb.x, v1 = xa.y + xb.y, v2 = xa.z + xb.z, v3 = xa.w + xb.w;
  float s = v0 + v1 + v2 + v3;
  float sq = v0 * v0 + v1 * v1 + v2 * v2 + v3 * v3;
#pragma unroll
  for (int off = 1; off < 64; off <<= 1) {
    s  += __shfl_xor(s, off);
    sq += __shfl_xor(sq, off);
  }
  __shared__ float red[8];
  int wave = tid >> 6;
  if ((tid & 63) == 0) { red[wave * 2] = s; red[wave * 2 + 1] = sq; }
  __syncthreads();
  s  = red[0] + red[2] + red[4] + red[6];
  sq = red[1] + red[3] + red[5] + red[7];
  float mean = s * (1.0f / D_MODEL);
  float var = sq * (1.0f / D_MODEL) - mean * mean;
  float inv = rsqrtf(var + 1e-8f);
  float4 g  = *(const float4*)(gamma + tid * 4);
  float4 be = *(const float4*)(beta + tid * 4);
  float o0 = (v0 - mean) * inv * g.x + be.x;
  float o1 = (v1 - mean) * inv * g.y + be.y;
  float o2 = (v2 - mean) * inv * g.z + be.z;
  float o3 = (v3 - mean) * inv * g.w + be.w;
  float4 of; of.x = o0; of.y = o1; of.z = o2; of.w = o3;
  *(float4*)(outf + base) = of;
  if (WRITE_BF16) {
    ushort4 ub; ub.x = f2bf(o0); ub.y = f2bf(o1); ub.z = f2bf(o2); ub.w = f2bf(o3);
    *(ushort4*)(outb + base) = ub;
  }
}

extern "C" void kernel_launch(void* const* d_in, const int* in_sizes, int n_in,
                              void* d_out, int out_size, void* d_ws, size_t ws_size,
                              hipStream_t stream) {
  const float* x     = (const float*)d_in[0];
  const float* wq    = (const float*)d_in[1];
  const float* bq    = (const float*)d_in[2];
  const float* wk    = (const float*)d_in[3];
  const float* bk    = (const float*)d_in[4];
  const float* wv    = (const float*)d_in[5];
  const float* bv    = (const float*)d_in[6];
  const float* wo    = (const float*)d_in[7];
  const float* bo    = (const float*)d_in[8];
  const float* w1    = (const float*)d_in[9];
  const float* b1    = (const float*)d_in[10];
  const float* w2    = (const float*)d_in[11];
  const float* b2    = (const float*)d_in[12];
  const float* gamma = (const float*)d_in[13];
  const float* beta  = (const float*)d_in[14];

  char* ws = (char*)d_ws;
  const size_t MB = 1ull << 20;
  // buffer plan — phase-aliased (stream order guarantees no overlap-in-time):
  //   [0,16)   xb (cast->QKV)  /  out1b (LN1->FFN1)
  //   [0,32)   ffn2 partials (FFN2->LN2; overwrites dead xb/out1b AND dead wqkvT/woT/w1T)
  //   [16,22)  wqkvT  [22,24) woT  [24,32) w1T  [32,40) w2T  [40,41) bqkv
  //   [41,89)  qkvb (QKV->attn) / attnoutb@41 (outproj->LN1) / h1@[41,105) (FFN1->FFN2)
  //   [89,105) Vt_g (->attn)
  //   [105,121) ctx (attn->outproj)
  //   [121,153) out1f (LN1->LN2)
  unsigned short* xb      = (unsigned short*)(ws + 0 * MB);
  unsigned short* out1b   = (unsigned short*)(ws + 0 * MB);
  unsigned short* ffn2    = (unsigned short*)(ws + 0 * MB);    // 32 MB: two bf16 partials
  unsigned short* wqkvT   = (unsigned short*)(ws + 16 * MB);
  unsigned short* woT     = (unsigned short*)(ws + 22 * MB);
  unsigned short* w1T     = (unsigned short*)(ws + 24 * MB);
  unsigned short* w2T     = (unsigned short*)(ws + 32 * MB);
  float*          bqkv    = (float*)(ws + 40 * MB);
  unsigned short* qkvb    = (unsigned short*)(ws + 41 * MB);
  unsigned short* attnoutb= (unsigned short*)(ws + 41 * MB);
  unsigned short* h1      = (unsigned short*)(ws + 41 * MB);
  unsigned short* Vt_g    = (unsigned short*)(ws + 89 * MB);
  unsigned short* ctx     = (unsigned short*)(ws + 105 * MB);
  float*          out1f   = (float*)(ws + 121 * MB);

  // preprocessing (3 launches; transpose grid is exact: 12288 tiles)
  cast_kernel<<<(MTOT * D_MODEL / 4 + 255) / 256, 256, 0, stream>>>(x, xb, MTOT * D_MODEL / 4);
  transpose_weights_kernel<<<12288, 256, 0, stream>>>(
      wq, wk, wv, wo, w1, w2, wqkvT, woT, w1T, w2T);
  bias_concat_kernel<<<12, 256, 0, stream>>>(bq, bk, bv, bqkv);

  // fused QKV projection: [8192][3072] — 256^2 8-phase kernel (384 wg, %8==0)
  gemm256_bt_kernel<0, 1, 1, 1><<<(3072 / 256) * (MTOT / 256), 512, 0, stream>>>(
      xb, wqkvT, bqkv, qkvb, MTOT, 3072, D_MODEL);
  // V -> Vt_g[bh][dh][kv]
  transpose_v_kernel<<<dim3(SEQ / 32, DH / 32, BATCH * NHEAD), 256, 0, stream>>>(qkvb, Vt_g);
  // attention: 128 q/block, 32 q/wave; grid.x = bh (q-blocks of one bh share an XCD's L2)
  attn_kernel<<<dim3(BATCH * NHEAD, SEQ / 128), 256, 0, stream>>>(qkvb, Vt_g, ctx);

  // out-proj stays on 128^2 kernel (N=1024 -> only 128 wg at 256^2; grid too small)
  gemm_bt_kernel<0, 1, 1, 1><<<(D_MODEL / 128) * (MTOT / 128), 256, 0, stream>>>(
      ctx, woT, bo, attnoutb, MTOT, D_MODEL, D_MODEL);
  ln_kernel<1, 1, 0><<<MTOT, 256, 0, stream>>>(
      x, attnoutb, nullptr, nullptr, gamma, beta, out1f, out1b);
  // FFN1: 256^2 8-phase (512 wg = exactly 2 rounds at 1 block/CU)
  gemm256_bt_kernel<1, 1, 1, 1><<<(DFF / 256) * (MTOT / 256), 512, 0, stream>>>(
      out1b, w1T, b1, h1, MTOT, DFF, D_MODEL);
  // FFN2 split-K=2: 256 wg (exactly 1/CU), bf16 partials; bias b2 folded into LN2
  gemm256_bt_kernel<0, 1, 2, 0><<<2 * (D_MODEL / 256) * (MTOT / 256), 512, 0, stream>>>(
      h1, w2T, nullptr, ffn2, MTOT, D_MODEL, DFF);
  ln_kernel<1, 0, 1><<<MTOT, 256, 0, stream>>>(
      out1f, ffn2, ffn2 + (size_t)MTOT * D_MODEL, b2, gamma, beta, (float*)d_out, nullptr);
}

// Round 2
// 541.463 us; speedup vs baseline: 1.0609x; 1.0036x over previous
//
#include <hip/hip_runtime.h>
#include <stdint.h>

#define D_MODEL 1024
#define NHEAD 16
#define DH 64
#define DFF 4096
#define BATCH 4
#define SEQ 2048
#define MTOT (BATCH*SEQ)   // 8192 rows total

// Q pre-scale folds 1/sqrt(Dh) AND log2(e) so softmax is a bare v_exp_f32 (exp2):
//   s' = s * log2e;  p = exp2(min(s', 10*log2e)) = exp(min(s,10))
#define QSCALE 0.18033688011112043f   // 0.125 * log2(e)
#define CLIP2  14.426950408889634f    // 10 * log2(e)

typedef short short8 __attribute__((ext_vector_type(8)));
typedef float f32x4 __attribute__((ext_vector_type(4)));
typedef unsigned int uint;

__device__ inline unsigned short f2bf(float f) {
  union { float f; unsigned u; } v; v.f = f;
  unsigned r = v.u + 0x7fffu + ((v.u >> 16) & 1u);
  return (unsigned short)(r >> 16);
}
__device__ inline float bf2f(unsigned short b) {
  union { unsigned u; float f; } v; v.u = ((unsigned)b) << 16;
  return v.f;
}
// truncation-pack two floats to bf16 pair in one dword: [lo | hi<<16]
__device__ inline unsigned pack_trunc(float lo, float hi) {
  union { float f; unsigned u; } a, b; a.f = lo; b.f = hi;
  return __builtin_amdgcn_perm(b.u, a.u, 0x07060302u);
}
// async 16B global -> LDS (wave-uniform base + lane*16 contract)
__device__ __forceinline__ void async16(const unsigned short* g, unsigned short* l) {
  __builtin_amdgcn_global_load_lds(
      (const __attribute__((address_space(1))) unsigned int*)g,
      (__attribute__((address_space(3))) unsigned int*)l, 16, 0, 0);
}

// ---------------- cast x -> bf16 ----------------
__global__ void cast_kernel(const float* __restrict__ in, unsigned short* __restrict__ out, int n4) {
  int i = blockIdx.x * blockDim.x + threadIdx.x;
  if (i < n4) {
    float4 v = ((const float4*)in)[i];
    ushort4 o;
    o.x = f2bf(v.x); o.y = f2bf(v.y); o.z = f2bf(v.z); o.w = f2bf(v.w);
    ((ushort4*)out)[i] = o;
  }
}

// ------------- ALL weight transposes, ONE launch, 64x64 tiles (3072 blocks) -------------
// tiles: [0,1024): wq|wk|wv|wo (256 each); [1024,2048): w1; [2048,3072): w2
// load: float4 (16B/lane, 256B/row) ; write: uint4 along K (128B full-line rows)
__global__ void transpose_weights_kernel(
    const float* __restrict__ wq, const float* __restrict__ wk,
    const float* __restrict__ wv, const float* __restrict__ wo,
    const float* __restrict__ w1, const float* __restrict__ w2,
    unsigned short* __restrict__ wqkvT, unsigned short* __restrict__ woT,
    unsigned short* __restrict__ w1T, unsigned short* __restrict__ w2T) {
  __shared__ __align__(16) unsigned short tile[64][72];   // stride 144B = 9*16B (aligned b128)
  const int id = blockIdx.x;
  const float* in; unsigned short* out; int K, N, n0, k0; float scale = 1.0f;
  if (id < 1024) {
    const int wi = id >> 8, t = id & 255;
    switch (wi) {
      case 0:  in = wq; out = wqkvT;           scale = QSCALE; break;
      case 1:  in = wk; out = wqkvT + 1048576; break;
      case 2:  in = wv; out = wqkvT + 2097152; break;
      default: in = wo; out = woT;             break;
    }
    K = 1024; N = 1024; n0 = (t & 15) * 64; k0 = (t >> 4) * 64;
  } else if (id < 2048) {
    const int t = id - 1024;
    in = w1; out = w1T; K = 1024; N = 4096; n0 = (t & 63) * 64; k0 = (t >> 6) * 64;
  } else {
    const int t = id - 2048;
    in = w2; out = w2T; K = 4096; N = 1024; n0 = (t & 15) * 64; k0 = (t >> 4) * 64;
  }
  const int tx = threadIdx.x & 15, ty = threadIdx.x >> 4;  // 16 x 16
#pragma unroll
  for (int j = 0; j < 64; j += 16) {
    float4 v = *(const float4*)(in + (size_t)(k0 + ty + j) * N + n0 + tx * 4);
    tile[tx * 4 + 0][ty + j] = f2bf(v.x * scale);
    tile[tx * 4 + 1][ty + j] = f2bf(v.y * scale);
    tile[tx * 4 + 2][ty + j] = f2bf(v.z * scale);
    tile[tx * 4 + 3][ty + j] = f2bf(v.w * scale);
  }
  __syncthreads();
  const int r = threadIdx.x >> 3, c = threadIdx.x & 7;     // 32 x 8
#pragma unroll
  for (int j = 0; j < 64; j += 32)
    *(uint4*)(out + (size_t)(n0 + r + j) * K + k0 + c * 8) =
        *(const uint4*)(&tile[r + j][c * 8]);
}

// ------------- concat + scale biases into [3072] -------------
__global__ void bias_concat_kernel(const float* __restrict__ bq, const float* __restrict__ bk,
                                   const float* __restrict__ bv, float* __restrict__ o) {
  int i = blockIdx.x * 256 + threadIdx.x;
  if (i < 3 * D_MODEL) {
    float v = (i < D_MODEL) ? bq[i] * QSCALE
            : (i < 2 * D_MODEL) ? bk[i - D_MODEL] : bv[i - 2 * D_MODEL];
    o[i] = v;
  }
}

// ------------- transpose V (from qkv cols 2048..3071) into Vt_g[bh][dh][kv] -------------
__global__ void transpose_v_kernel(const unsigned short* __restrict__ QKV,
                                   unsigned short* __restrict__ Vt) {
  __shared__ unsigned short tile[32][33];
  int bh = blockIdx.z, b = bh >> 4, h = bh & 15;
  int kv0 = blockIdx.x * 32, dh0 = blockIdx.y * 32;
  int tx = threadIdx.x & 31, ty = threadIdx.x >> 5;  // 32 x 8
#pragma unroll
  for (int j = 0; j < 32; j += 8)
    tile[ty + j][tx] = QKV[(size_t)(b * SEQ + kv0 + ty + j) * 3072 + 2048 + h * DH + dh0 + tx];
  __syncthreads();
#pragma unroll
  for (int j = 0; j < 32; j += 8)
    Vt[(size_t)(bh * DH + dh0 + ty + j) * SEQ + kv0 + tx] = tile[tx][ty + j];
}

// ------------- GEMM 256x256, 8-phase counted-vmcnt schedule (T2+T3+T4+T5) -------------
// 512 threads = 8 waves (2 m x 4 n), per-wave C = 128x64 (acc[8][4]).
// LDS: double-buffered A[256][64]+B[256][64] bf16 = 128 KiB -> 1 block/CU, 2 waves/SIMD.
// Swizzle: 16B slot s of row r holds logical slot s^(r&7); applied on the GLOBAL source
// of global_load_lds (linear LDS dest, wave-uniform contract) and on the ds_read side.
// Per K-tile: 4 phases x 16 MFMA, raw s_barrier pairs, setprio(1) around MFMA cluster.
// Staging of K-tile t+2 spread 2 bands/phase in WAR-safe order; ONE s_waitcnt vmcnt(6)
// per K-tile (never 0 in steady state; vmcnt(0) only in the last 2 tail iterations).
#define MFMA_Q(mh, nh)                                                                     \
  _Pragma("unroll")                                                                        \
  for (int ks = 0; ks < 2; ks++) {                                                         \
    _Pragma("unroll")                                                                      \
    for (int i = 0; i < 4; i++) {                                                          \
      _Pragma("unroll")                                                                    \
      for (int nn = 0; nn < 2; nn++) {                                                     \
        acc[(mh)*4 + i][(nh)*2 + nn] = __builtin_amdgcn_mfma_f32_16x16x32_bf16(            \
            af[i][ks], bf[(nh)*2 + nn][ks], acc[(mh)*4 + i][(nh)*2 + nn], 0, 0, 0);        \
      }                                                                                    \
    }                                                                                      \
  }

template<int RELU, int OUT_BF16, int KSPLIT, int BIAS>
__global__ __launch_bounds__(512, 2) void gemm256_bt_kernel(
    const unsigned short* __restrict__ A,
    const unsigned short* __restrict__ Bt,
    const float* __restrict__ bias,
    void* __restrict__ Cout,
    int M, int N, int K) {
  __shared__ __align__(16) unsigned short lds[65536];   // 128 KiB: [buf][A 16384 | B 16384]

  // XCD-compact bijective swizzle (grid always a multiple of 8)
  const int nwg = gridDim.x;
  int nid = (blockIdx.x & 7) * (nwg >> 3) + (blockIdx.x >> 3);
  int kh = 0;
  if (KSPLIT == 2) { kh = nid & 1; nid >>= 1; }
  const int GX = N >> 8;
  const int im = nid / GX, in_ = nid % GX;
  const int m0 = im * 256, n0 = in_ * 256;

  const int tid = threadIdx.x;
  const int lane = tid & 63, wave = tid >> 6;
  const int wm = (wave >> 2) * 128, wn = (wave & 3) * 64;
  const int lm = lane & 15, lg = lane >> 4;
  const int rot = lm & 7;
  const int aoff0 = ((lg) ^ rot) << 3;        // elem offset of 16B slot, k-slice 0
  const int aoff1 = ((4 + lg) ^ rot) << 3;    // k-slice 1
  const int arow = (wm + lm) << 6;            // A frag row base (elements)
  const int brow = (wn + lm) << 6;            // B frag row base

  const int kbeg = (KSPLIT == 2) ? kh * (K >> 1) : 0;
  const int nk = ((KSPLIT == 2) ? (K >> 1) : K) >> 6;   // #K-tiles (>=2 for all uses)

  // staging: thread tid covers row rb=tid>>3 of a 64-row band, phys 16B slot tid&7;
  // global source column pre-swizzled so linear LDS dest yields swizzled layout.
  const int rb = tid >> 3;
  const int gcol = (((tid & 7) ^ (rb & 7)) << 3);
  const unsigned short* gA = A  + (size_t)(m0 + rb) * K + kbeg + gcol;
  const unsigned short* gB = Bt + (size_t)(n0 + rb) * K + kbeg + gcol;

  auto stage = [&](const unsigned short* g, int b, int st, unsigned short* seg) {
    async16(g + (size_t)b * 64 * K + (size_t)st * 64, seg + b * 4096 + tid * 8);
  };

  f32x4 acc[8][4] = {};

  // ---- prologue: K0 full (8 bands) + K1 first 6 bands; seal K0 with vmcnt(6) ----
  {
    unsigned short* A0s = lds;
    unsigned short* B0s = lds + 16384;
    unsigned short* A1s = lds + 32768;
    unsigned short* B1s = lds + 49152;
    stage(gA, 0, 0, A0s); stage(gA, 2, 0, A0s);
    stage(gB, 0, 0, B0s); stage(gB, 1, 0, B0s);
    stage(gA, 1, 0, A0s); stage(gA, 3, 0, A0s);
    stage(gB, 2, 0, B0s); stage(gB, 3, 0, B0s);
    stage(gA, 0, 1, A1s); stage(gA, 2, 1, A1s);
    stage(gB, 0, 1, B1s); stage(gB, 1, 1, B1s);
    stage(gA, 1, 1, A1s); stage(gA, 3, 1, A1s);
    __builtin_amdgcn_s_waitcnt(0x0F76);   // vmcnt(6): K0 landed, K1's 6 in flight
    __builtin_amdgcn_s_barrier();
  }

  for (int t = 0; t < nk; ++t) {
    const int cur = t & 1;
    unsigned short* LA = lds + (cur << 15);
    unsigned short* LB = LA + 16384;
    unsigned short* NA = lds + ((cur ^ 1) << 15);
    unsigned short* NB = NA + 16384;
    short8 af[4][2], bf[4][2];

    // ---------- phase 0: (m-half0, n-half0) ----------
    if (t + 1 < nk) { stage(gB, 2, t + 1, NB); stage(gB, 3, t + 1, NB); }
#pragma unroll
    for (int i = 0; i < 4; i++) {
      af[i][0] = *(const short8*)(LA + arow + i * 1024 + aoff0);
      af[i][1] = *(const short8*)(LA + arow + i * 1024 + aoff1);
    }
#pragma unroll
    for (int n = 0; n < 2; n++) {
      bf[n][0] = *(const short8*)(LB + brow + n * 1024 + aoff0);
      bf[n][1] = *(const short8*)(LB + brow + n * 1024 + aoff1);
    }
    __builtin_amdgcn_s_barrier();
    __builtin_amdgcn_s_setprio(1);
    MFMA_Q(0, 0);
    __builtin_amdgcn_s_setprio(0);
    __builtin_amdgcn_s_barrier();

    // ---------- phase 1: (m-half0, n-half1) ----------
    if (t + 2 < nk) { stage(gA, 0, t + 2, LA); stage(gA, 2, t + 2, LA); }
#pragma unroll
    for (int n = 2; n < 4; n++) {
      bf[n][0] = *(const short8*)(LB + brow + n * 1024 + aoff0);
      bf[n][1] = *(const short8*)(LB + brow + n * 1024 + aoff1);
    }
    __builtin_amdgcn_s_barrier();
    __builtin_amdgcn_s_setprio(1);
    MFMA_Q(0, 1);
    __builtin_amdgcn_s_setprio(0);
    __builtin_amdgcn_s_barrier();

    // ---------- phase 2: (m-half1, n-half1) ----------
    if (t + 2 < nk) { stage(gB, 0, t + 2, LB); stage(gB, 1, t + 2, LB); }
#pragma unroll
    for (int i = 0; i < 4; i++) {
      af[i][0] = *(const short8*)(LA + arow + 4096 + i * 1024 + aoff0);
      af[i][1] = *(const short8*)(LA + arow + 4096 + i * 1024 + aoff1);
    }
    __builtin_amdgcn_s_barrier();
    __builtin_amdgcn_s_setprio(1);
    MFMA_Q(1, 1);
    __builtin_amdgcn_s_setprio(0);
    __builtin_amdgcn_s_barrier();

    // ---------- phase 3: (m-half1, n-half0); seal next K-tile ----------
    if (t + 2 < nk) {
      stage(gA, 1, t + 2, LA); stage(gA, 3, t + 2, LA);
      __builtin_amdgcn_s_waitcnt(0x0F76);   // vmcnt(6): K-tile t+1 fully landed
    } else {
      __builtin_amdgcn_s_waitcnt(0x0F70);   // tail: vmcnt(0)
    }
    __builtin_amdgcn_s_barrier();
    __builtin_amdgcn_s_setprio(1);
    MFMA_Q(1, 0);
    __builtin_amdgcn_s_setprio(0);
    __builtin_amdgcn_s_barrier();
  }

  // ---- epilogue: C/D layout col=lane&15, row=(lane>>4)*4+r ----
  unsigned short* Cb = (unsigned short*)Cout + (KSPLIT == 2 ? (size_t)kh * M * N : 0);
#pragma unroll
  for (int nt = 0; nt < 4; nt++) {
    int col = n0 + wn + nt * 16 + lm;
    float bv = BIAS ? bias[col] : 0.0f;
#pragma unroll
    for (int mf = 0; mf < 8; mf++) {
#pragma unroll
      for (int r = 0; r < 4; r++) {
        int row = m0 + wm + mf * 16 + lg * 4 + r;
        float v = acc[mf][nt][r] + bv;
        if (RELU) v = fmaxf(v, 0.0f);
        if (OUT_BF16) Cb[(size_t)row * N + col] = f2bf(v);
        else          ((float*)Cout)[(size_t)row * N + col] = v;
      }
    }
  }
}

// ------------- attention: 256 q/block, 8 waves, 2 blocks/CU, async double-buffered K/V -------------
// T3/T4 pipeline: K/V staged via global_load_lds with PRE-SWIZZLED global source
// (linear LDS dest, wave-uniform contract); double-buffered; ONE raw s_barrier per
// 64-kv tile: {vmcnt(0) [fully covered by previous compute]; barrier; issue t+1 loads
// into other buffer; compute}. Zero VALU on staging, load latency fully hidden.
// S^T = K*Q^T; p = exp2(min(s',CLIP2)); rowsum via MFMA vs ones; per-wave Ps roundtrip
// (lgkm-only wait 0xC07F, does NOT drain in-flight async loads). T5 setprio on MFMA.
__global__ __launch_bounds__(512, 4) void attn_kernel(
    const unsigned short* __restrict__ QKV,   // [8192][3072]: q|k|v
    const unsigned short* __restrict__ Vt_g,  // [64 bh][64 dh][2048 kv]
    unsigned short* __restrict__ ctx) {       // [8192][1024]
  __shared__ __align__(16) unsigned short Ks[2][4096];     // [buf][kv][dh] swizzled
  __shared__ __align__(16) unsigned short Vs[2][4096];     // [buf][dh][kv] swizzled
  __shared__ __align__(16) unsigned short Ps[8 * 2048];    // per-wave [q][kv] swizzled
  const int bh = blockIdx.x, b = bh >> 4, h = bh & 15;
  const int q0 = blockIdx.y * 256;
  const int tid = threadIdx.x, wave = tid >> 6, lane = tid & 63;
  const int lm = lane & 15, lq = lane >> 4;
  const int rot = (lm & 7) * 8;

  short8 qf[2][2];
#pragma unroll
  for (int ntq = 0; ntq < 2; ntq++) {
    const unsigned short* qp =
        QKV + (size_t)(b * SEQ + q0 + wave * 32 + ntq * 16 + lm) * 3072 + h * DH;
#pragma unroll
    for (int sl = 0; sl < 2; sl++) qf[ntq][sl] = *(const short8*)(qp + sl * 32 + lq * 8);
  }
  const short8 ones = {0x3F80, 0x3F80, 0x3F80, 0x3F80, 0x3F80, 0x3F80, 0x3F80, 0x3F80};
  f32x4 oacc[2][4] = {};
  f32x4 lsum[2] = {};

  // staging: thread covers row srow (0..63), phys 16B slot (tid&7); source column
  // pre-swizzled (slot ^ row&7) so the linear LDS dest lands in the swizzled layout.
  const int srow = tid >> 3;
  const int ssl = (tid & 7) ^ (srow & 7);
  const unsigned short* kg =
      QKV + (size_t)(b * SEQ + srow) * 3072 + D_MODEL + h * DH + ssl * 8;
  const unsigned short* vg = Vt_g + (size_t)(bh * DH + srow) * SEQ + ssl * 8;
  unsigned short* kdst = &Ks[0][0] + tid * 8;
  unsigned short* vdst = &Vs[0][0] + tid * 8;

  // prologue: tile 0 -> buf 0
  async16(kg, kdst);
  async16(vg, vdst);

  for (int it = 0; it < SEQ / 64; it++) {
    const int buf = it & 1;
    __builtin_amdgcn_s_waitcnt(0x0F70);   // vmcnt(0): my tile-it loads landed (issued last iter)
    __builtin_amdgcn_s_barrier();         // all waves: loads landed + prev-iter reads done
    __builtin_amdgcn_sched_barrier(0);    // pin: nothing below moves above the barrier
    if (it + 1 < SEQ / 64) {              // issue next tile into other buffer; overlaps compute
      const int nb = (buf ^ 1) * 4096;
      async16(kg + (size_t)(it + 1) * 64 * 3072, kdst + nb);
      async16(vg + (it + 1) * 64, vdst + nb);
    }
    const unsigned short* Kb = &Ks[buf][0];
    const unsigned short* Vb = &Vs[buf][0];

    // S^T = K * Q^T ; p = exp2(min(s',CLIP2)); truncation-pack to per-wave Ps
#pragma unroll
    for (int mt = 0; mt < 4; mt++) {
      const unsigned short* krow = Kb + (mt * 16 + lm) * 64;
      short8 kf0 = *(const short8*)(krow + ((lq * 8) ^ rot));
      short8 kf1 = *(const short8*)(krow + ((32 + lq * 8) ^ rot));
#pragma unroll
      for (int ntq = 0; ntq < 2; ntq++) {
        f32x4 sa = {0.f, 0.f, 0.f, 0.f};
        __builtin_amdgcn_s_setprio(1);
        sa = __builtin_amdgcn_mfma_f32_16x16x32_bf16(kf0, qf[ntq][0], sa, 0, 0, 0);
        sa = __builtin_amdgcn_mfma_f32_16x16x32_bf16(kf1, qf[ntq][1], sa, 0, 0, 0);
        __builtin_amdgcn_s_setprio(0);
        float p0 = exp2f(fminf(sa[0], CLIP2));
        float p1 = exp2f(fminf(sa[1], CLIP2));
        float p2 = exp2f(fminf(sa[2], CLIP2));
        float p3 = exp2f(fminf(sa[3], CLIP2));
        uint2 d;
        d.x = pack_trunc(p0, p1);
        d.y = pack_trunc(p2, p3);
        *(uint2*)(Ps + wave * 2048 + (ntq * 16 + lm) * 64 + ((mt * 16 + lq * 4) ^ rot)) = d;
      }
    }
    // wave-local LDS RAW: wait lgkmcnt(0) only (vmcnt=63, expcnt=7 -> 0xC07F)
    __builtin_amdgcn_s_waitcnt(0xC07F);
    short8 pf[2][2];
#pragma unroll
    for (int mq = 0; mq < 2; mq++)
#pragma unroll
      for (int sl = 0; sl < 2; sl++)
        pf[mq][sl] = *(const short8*)(Ps + wave * 2048 + (mq * 16 + lm) * 64 + ((sl * 32 + lq * 8) ^ rot));
    __builtin_amdgcn_s_setprio(1);
#pragma unroll
    for (int nt = 0; nt < 4; nt++) {
      const unsigned short* vrow = Vb + (nt * 16 + lm) * 64;
      short8 vf0 = *(const short8*)(vrow + ((lq * 8) ^ rot));
      short8 vf1 = *(const short8*)(vrow + ((32 + lq * 8) ^ rot));
#pragma unroll
      for (int mq = 0; mq < 2; mq++) {
        oacc[mq][nt] = __builtin_amdgcn_mfma_f32_16x16x32_bf16(pf[mq][0], vf0, oacc[mq][nt], 0, 0, 0);
        oacc[mq][nt] = __builtin_amdgcn_mfma_f32_16x16x32_bf16(pf[mq][1], vf1, oacc[mq][nt], 0, 0, 0);
      }
    }
#pragma unroll
    for (int mq = 0; mq < 2; mq++) {
      lsum[mq] = __builtin_amdgcn_mfma_f32_16x16x32_bf16(pf[mq][0], ones, lsum[mq], 0, 0, 0);
      lsum[mq] = __builtin_amdgcn_mfma_f32_16x16x32_bf16(pf[mq][1], ones, lsum[mq], 0, 0, 0);
    }
    __builtin_amdgcn_s_setprio(0);
    // no trailing barrier: next iteration's top barrier seals reads before restaging
  }

#pragma unroll
  for (int mq = 0; mq < 2; mq++) {
    float linv[4];
#pragma unroll
    for (int r = 0; r < 4; r++) linv[r] = 1.0f / lsum[mq][r];
    const size_t rowbase =
        (size_t)(b * SEQ + q0 + wave * 32 + mq * 16 + lq * 4) * D_MODEL + h * DH;
#pragma unroll
    for (int nt = 0; nt < 4; nt++) {
#pragma unroll
      for (int r = 0; r < 4; r++) {
        ctx[rowbase + (size_t)r * D_MODEL + nt * 16 + lm] = f2bf(oacc[mq][nt][r] * linv[r]);
      }
    }
  }
}

// ------------- residual + layernorm -------------
// THREE=1: out = LN(A + bf16(B1) + bf16(B2) + cbias)  (split-K partial merge + bias)
template<int B_BF16, int WRITE_BF16, int THREE>
__global__ void ln_kernel(const float* __restrict__ A, const void* __restrict__ Bv,
                          const void* __restrict__ B2v, const float* __restrict__ cbias,
                          const float* __restrict__ gamma, const float* __restrict__ beta,
                          float* __restrict__ outf, unsigned short* __restrict__ outb) {
  const int row = blockIdx.x;
  const int tid = threadIdx.x;
  const size_t base = (size_t)row * D_MODEL + tid * 4;
  float4 xa = *(const float4*)(A + base);
  float4 xb;
  if (B_BF16) {
    ushort4 u = *(const ushort4*)((const unsigned short*)Bv + base);
    xb.x = bf2f(u.x); xb.y = bf2f(u.y); xb.z = bf2f(u.z); xb.w = bf2f(u.w);
  } else {
    xb = *(const float4*)((const float*)Bv + base);
  }
  if (THREE) {
    ushort4 u2 = *(const ushort4*)((const unsigned short*)B2v + base);
    float4 cb = *(const float4*)(cbias + tid * 4);
    xb.x += bf2f(u2.x) + cb.x; xb.y += bf2f(u2.y) + cb.y;
    xb.z += bf2f(u2.z) + cb.z; xb.w += bf2f(u2.w) + cb.w;
  }
  float v0 = xa.x + xb.x, v1 = xa.y + xb.y, v2 = xa.z + xb.z, v3 = xa.w + xb.w;
  float s = v0 + v1 + v2 + v3;
  float sq = v0 * v0 + v1 * v1 + v2 * v2 + v3 * v3;
#pragma unroll
  for (int off = 1; off < 64; off <<= 1) {
    s  += __shfl_xor(s, off);
    sq += __shfl_xor(sq, off);
  }
  __shared__ float red[8];
  int wave = tid >> 6;
  if ((tid & 63) == 0) { red[wave * 2] = s; red[wave * 2 + 1] = sq; }
  __syncthreads();
  s  = red[0] + red[2] + red[4] + red[6];
  sq = red[1] + red[3] + red[5] + red[7];
  float mean = s * (1.0f / D_MODEL);
  float var = sq * (1.0f / D_MODEL) - mean * mean;
  float inv = rsqrtf(var + 1e-8f);
  float4 g  = *(const float4*)(gamma + tid * 4);
  float4 be = *(const float4*)(beta + tid * 4);
  float o0 = (v0 - mean) * inv * g.x + be.x;
  float o1 = (v1 - mean) * inv * g.y + be.y;
  float o2 = (v2 - mean) * inv * g.z + be.z;
  float o3 = (v3 - mean) * inv * g.w + be.w;
  float4 of; of.x = o0; of.y = o1; of.z = o2; of.w = o3;
  *(float4*)(outf + base) = of;
  if (WRITE_BF16) {
    ushort4 ub; ub.x = f2bf(o0); ub.y = f2bf(o1); ub.z = f2bf(o2); ub.w = f2bf(o3);
    *(ushort4*)(outb + base) = ub;
  }
}

extern "C" void kernel_launch(void* const* d_in, const int* in_sizes, int n_in,
                              void* d_out, int out_size, void* d_ws, size_t ws_size,
                              hipStream_t stream) {
  const float* x     = (const float*)d_in[0];
  const float* wq    = (const float*)d_in[1];
  const float* bq    = (const float*)d_in[2];
  const float* wk    = (const float*)d_in[3];
  const float* bk    = (const float*)d_in[4];
  const float* wv    = (const float*)d_in[5];
  const float* bv    = (const float*)d_in[6];
  const float* wo    = (const float*)d_in[7];
  const float* bo    = (const float*)d_in[8];
  const float* w1    = (const float*)d_in[9];
  const float* b1    = (const float*)d_in[10];
  const float* w2    = (const float*)d_in[11];
  const float* b2    = (const float*)d_in[12];
  const float* gamma = (const float*)d_in[13];
  const float* beta  = (const float*)d_in[14];

  char* ws = (char*)d_ws;
  const size_t MB = 1ull << 20;
  // buffer plan — phase-aliased (stream order guarantees no overlap-in-time):
  //   [0,16)   xb (cast->QKV)  /  out1b (LN1->FFN1)
  //   [0,32)   ffn2 partials (FFN2->LN2)
  //   [16,22)  wqkvT  [22,24) woT  [24,32) w1T  [32,40) w2T  [40,41) bqkv
  //   [41,89)  qkvb (QKV->attn) / oprojp 32MB@41 (outproj->LN1) / h1@[41,105) (FFN1->FFN2)
  //   [89,105) Vt_g (->attn)
  //   [105,121) ctx (attn->outproj)
  //   [121,153) out1f (LN1->LN2)
  unsigned short* xb      = (unsigned short*)(ws + 0 * MB);
  unsigned short* out1b   = (unsigned short*)(ws + 0 * MB);
  unsigned short* ffn2    = (unsigned short*)(ws + 0 * MB);    // 32 MB: two bf16 partials
  unsigned short* wqkvT   = (unsigned short*)(ws + 16 * MB);
  unsigned short* woT     = (unsigned short*)(ws + 22 * MB);
  unsigned short* w1T     = (unsigned short*)(ws + 24 * MB);
  unsigned short* w2T     = (unsigned short*)(ws + 32 * MB);
  float*          bqkv    = (float*)(ws + 40 * MB);
  unsigned short* qkvb    = (unsigned short*)(ws + 41 * MB);
  unsigned short* oprojp  = (unsigned short*)(ws + 41 * MB);   // 32 MB: two bf16 partials
  unsigned short* h1      = (unsigned short*)(ws + 41 * MB);
  unsigned short* Vt_g    = (unsigned short*)(ws + 89 * MB);
  unsigned short* ctx     = (unsigned short*)(ws + 105 * MB);
  float*          out1f   = (float*)(ws + 121 * MB);

  // preprocessing
  cast_kernel<<<(MTOT * D_MODEL / 4 + 255) / 256, 256, 0, stream>>>(x, xb, MTOT * D_MODEL / 4);
  transpose_weights_kernel<<<3072, 256, 0, stream>>>(
      wq, wk, wv, wo, w1, w2, wqkvT, woT, w1T, w2T);
  bias_concat_kernel<<<12, 256, 0, stream>>>(bq, bk, bv, bqkv);

  // fused QKV projection: [8192][3072] — 256^2 8-phase kernel (384 wg, %8==0)
  gemm256_bt_kernel<0, 1, 1, 1><<<(3072 / 256) * (MTOT / 256), 512, 0, stream>>>(
      xb, wqkvT, bqkv, qkvb, MTOT, 3072, D_MODEL);
  // V -> Vt_g[bh][dh][kv]
  transpose_v_kernel<<<dim3(SEQ / 32, DH / 32, BATCH * NHEAD), 256, 0, stream>>>(qkvb, Vt_g);
  // attention: 256 q/block, 8 waves, async double-buffered K/V; 512 wg = 2/CU exact
  attn_kernel<<<dim3(BATCH * NHEAD, SEQ / 256), 512, 0, stream>>>(qkvb, Vt_g, ctx);

  // out-proj: 256^2 split-K=2 (256 wg = exact 1 round); partials + bo merged in LN1
  gemm256_bt_kernel<0, 1, 2, 0><<<2 * (D_MODEL / 256) * (MTOT / 256), 512, 0, stream>>>(
      ctx, woT, nullptr, oprojp, MTOT, D_MODEL, D_MODEL);
  ln_kernel<1, 1, 1><<<MTOT, 256, 0, stream>>>(
      x, oprojp, oprojp + (size_t)MTOT * D_MODEL, bo, gamma, beta, out1f, out1b);
  // FFN1: 256^2 8-phase (512 wg = exactly 2 rounds at 1 block/CU)
  gemm256_bt_kernel<1, 1, 1, 1><<<(DFF / 256) * (MTOT / 256), 512, 0, stream>>>(
      out1b, w1T, b1, h1, MTOT, DFF, D_MODEL);
  // FFN2 split-K=2: 256 wg (exactly 1/CU), bf16 partials; bias b2 folded into LN2
  gemm256_bt_kernel<0, 1, 2, 0><<<2 * (D_MODEL / 256) * (MTOT / 256), 512, 0, stream>>>(
      h1, w2T, nullptr, ffn2, MTOT, D_MODEL, DFF);
  ln_kernel<1, 0, 1><<<MTOT, 256, 0, stream>>>(
      out1f, ffn2, ffn2 + (size_t)MTOT * D_MODEL, b2, gamma, beta, (float*)d_out, nullptr);
}

// Round 3
// 530.736 us; speedup vs baseline: 1.0823x; 1.0202x over previous
//
#include <hip/hip_runtime.h>
#include <stdint.h>

#define D_MODEL 1024
#define NHEAD 16
#define DH 64
#define DFF 4096
#define BATCH 4
#define SEQ 2048
#define MTOT (BATCH*SEQ)   // 8192 rows total

// Q pre-scale folds 1/sqrt(Dh) AND log2(e) so softmax is a bare v_exp_f32 (exp2):
//   s' = s * log2e;  p = exp2(min(s', 10*log2e)) = exp(min(s,10))
#define QSCALE 0.18033688011112043f   // 0.125 * log2(e)
#define CLIP2  14.426950408889634f    // 10 * log2(e)

typedef short short8 __attribute__((ext_vector_type(8)));
typedef float f32x4 __attribute__((ext_vector_type(4)));
typedef unsigned int uint;

__device__ inline unsigned short f2bf(float f) {
  union { float f; unsigned u; } v; v.f = f;
  unsigned r = v.u + 0x7fffu + ((v.u >> 16) & 1u);
  return (unsigned short)(r >> 16);
}
__device__ inline float bf2f(unsigned short b) {
  union { unsigned u; float f; } v; v.u = ((unsigned)b) << 16;
  return v.f;
}
// truncation-pack two floats to bf16 pair in one dword: [lo | hi<<16]
__device__ inline unsigned pack_trunc(float lo, float hi) {
  union { float f; unsigned u; } a, b; a.f = lo; b.f = hi;
  return __builtin_amdgcn_perm(b.u, a.u, 0x07060302u);
}
// raw hardware exp2 (v_exp_f32) — avoids the __ocml_exp2_f32 denorm-wrapper
// (~5 VALU instrs); identical results except for outputs < 2^-126 (irrelevant
// vs softmax rowsum).
__device__ __forceinline__ float hw_exp2(float x) {
  return __builtin_amdgcn_exp2f(x);
}
// async 16B global -> LDS (wave-uniform base + lane*16 contract)
__device__ __forceinline__ void async16(const unsigned short* g, unsigned short* l) {
  __builtin_amdgcn_global_load_lds(
      (const __attribute__((address_space(1))) unsigned int*)g,
      (__attribute__((address_space(3))) unsigned int*)l, 16, 0, 0);
}

// ---------------- cast x -> bf16 ----------------
__global__ void cast_kernel(const float* __restrict__ in, unsigned short* __restrict__ out, int n4) {
  int i = blockIdx.x * blockDim.x + threadIdx.x;
  if (i < n4) {
    float4 v = ((const float4*)in)[i];
    ushort4 o;
    o.x = f2bf(v.x); o.y = f2bf(v.y); o.z = f2bf(v.z); o.w = f2bf(v.w);
    ((ushort4*)out)[i] = o;
  }
}

// ------------- ALL weight transposes, ONE launch, 64x64 tiles (3072 blocks) -------------
// tiles: [0,1024): wq|wk|wv|wo (256 each); [1024,2048): w1; [2048,3072): w2
// load: float4 (16B/lane, 256B/row) ; write: uint4 along K (128B full-line rows)
__global__ void transpose_weights_kernel(
    const float* __restrict__ wq, const float* __restrict__ wk,
    const float* __restrict__ wv, const float* __restrict__ wo,
    const float* __restrict__ w1, const float* __restrict__ w2,
    unsigned short* __restrict__ wqkvT, unsigned short* __restrict__ woT,
    unsigned short* __restrict__ w1T, unsigned short* __restrict__ w2T) {
  __shared__ __align__(16) unsigned short tile[64][72];   // stride 144B = 9*16B (aligned b128)
  const int id = blockIdx.x;
  const float* in; unsigned short* out; int K, N, n0, k0; float scale = 1.0f;
  if (id < 1024) {
    const int wi = id >> 8, t = id & 255;
    switch (wi) {
      case 0:  in = wq; out = wqkvT;           scale = QSCALE; break;
      case 1:  in = wk; out = wqkvT + 1048576; break;
      case 2:  in = wv; out = wqkvT + 2097152; break;
      default: in = wo; out = woT;             break;
    }
    K = 1024; N = 1024; n0 = (t & 15) * 64; k0 = (t >> 4) * 64;
  } else if (id < 2048) {
    const int t = id - 1024;
    in = w1; out = w1T; K = 1024; N = 4096; n0 = (t & 63) * 64; k0 = (t >> 6) * 64;
  } else {
    const int t = id - 2048;
    in = w2; out = w2T; K = 4096; N = 1024; n0 = (t & 15) * 64; k0 = (t >> 4) * 64;
  }
  const int tx = threadIdx.x & 15, ty = threadIdx.x >> 4;  // 16 x 16
#pragma unroll
  for (int j = 0; j < 64; j += 16) {
    float4 v = *(const float4*)(in + (size_t)(k0 + ty + j) * N + n0 + tx * 4);
    tile[tx * 4 + 0][ty + j] = f2bf(v.x * scale);
    tile[tx * 4 + 1][ty + j] = f2bf(v.y * scale);
    tile[tx * 4 + 2][ty + j] = f2bf(v.z * scale);
    tile[tx * 4 + 3][ty + j] = f2bf(v.w * scale);
  }
  __syncthreads();
  const int r = threadIdx.x >> 3, c = threadIdx.x & 7;     // 32 x 8
#pragma unroll
  for (int j = 0; j < 64; j += 32)
    *(uint4*)(out + (size_t)(n0 + r + j) * K + k0 + c * 8) =
        *(const uint4*)(&tile[r + j][c * 8]);
}

// ------------- concat + scale biases into [3072] -------------
__global__ void bias_concat_kernel(const float* __restrict__ bq, const float* __restrict__ bk,
                                   const float* __restrict__ bv, float* __restrict__ o) {
  int i = blockIdx.x * 256 + threadIdx.x;
  if (i < 3 * D_MODEL) {
    float v = (i < D_MODEL) ? bq[i] * QSCALE
            : (i < 2 * D_MODEL) ? bk[i - D_MODEL] : bv[i - 2 * D_MODEL];
    o[i] = v;
  }
}

// ------------- transpose V (from qkv cols 2048..3071) into Vt_g[bh][dh][kv] -------------
__global__ void transpose_v_kernel(const unsigned short* __restrict__ QKV,
                                   unsigned short* __restrict__ Vt) {
  __shared__ unsigned short tile[32][33];
  int bh = blockIdx.z, b = bh >> 4, h = bh & 15;
  int kv0 = blockIdx.x * 32, dh0 = blockIdx.y * 32;
  int tx = threadIdx.x & 31, ty = threadIdx.x >> 5;  // 32 x 8
#pragma unroll
  for (int j = 0; j < 32; j += 8)
    tile[ty + j][tx] = QKV[(size_t)(b * SEQ + kv0 + ty + j) * 3072 + 2048 + h * DH + dh0 + tx];
  __syncthreads();
#pragma unroll
  for (int j = 0; j < 32; j += 8)
    Vt[(size_t)(bh * DH + dh0 + ty + j) * SEQ + kv0 + tx] = tile[tx][ty + j];
}

// ------------- GEMM 256x256, 8-phase counted-vmcnt schedule (T2+T3+T4+T5) -------------
// 512 threads = 8 waves (2 m x 4 n), per-wave C = 128x64 (acc[8][4]).
// LDS: double-buffered A[256][64]+B[256][64] bf16 = 128 KiB -> 1 block/CU, 2 waves/SIMD.
// Swizzle: 16B slot s of row r holds logical slot s^(r&7); applied on the GLOBAL source
// of global_load_lds (linear LDS dest, wave-uniform contract) and on the ds_read side.
// Per K-tile: 4 phases x 16 MFMA, raw s_barrier pairs, setprio(1) around MFMA cluster.
// Staging of K-tile t+2 spread 2 bands/phase in WAR-safe order; ONE s_waitcnt vmcnt(6)
// per K-tile (never 0 in steady state; vmcnt(0) only in the last 2 tail iterations).
#define MFMA_Q(mh, nh)                                                                     \
  _Pragma("unroll")                                                                        \
  for (int ks = 0; ks < 2; ks++) {                                                         \
    _Pragma("unroll")                                                                      \
    for (int i = 0; i < 4; i++) {                                                          \
      _Pragma("unroll")                                                                    \
      for (int nn = 0; nn < 2; nn++) {                                                     \
        acc[(mh)*4 + i][(nh)*2 + nn] = __builtin_amdgcn_mfma_f32_16x16x32_bf16(            \
            af[i][ks], bf[(nh)*2 + nn][ks], acc[(mh)*4 + i][(nh)*2 + nn], 0, 0, 0);        \
      }                                                                                    \
    }                                                                                      \
  }

template<int RELU, int OUT_BF16, int KSPLIT, int BIAS>
__global__ __launch_bounds__(512, 2) void gemm256_bt_kernel(
    const unsigned short* __restrict__ A,
    const unsigned short* __restrict__ Bt,
    const float* __restrict__ bias,
    void* __restrict__ Cout,
    int M, int N, int K) {
  __shared__ __align__(16) unsigned short lds[65536];   // 128 KiB: [buf][A 16384 | B 16384]

  // XCD-compact bijective swizzle (grid always a multiple of 8)
  const int nwg = gridDim.x;
  int nid = (blockIdx.x & 7) * (nwg >> 3) + (blockIdx.x >> 3);
  int kh = 0;
  if (KSPLIT == 2) { kh = nid & 1; nid >>= 1; }
  const int GX = N >> 8;
  const int im = nid / GX, in_ = nid % GX;
  const int m0 = im * 256, n0 = in_ * 256;

  const int tid = threadIdx.x;
  const int lane = tid & 63, wave = tid >> 6;
  const int wm = (wave >> 2) * 128, wn = (wave & 3) * 64;
  const int lm = lane & 15, lg = lane >> 4;
  const int rot = lm & 7;
  const int aoff0 = ((lg) ^ rot) << 3;        // elem offset of 16B slot, k-slice 0
  const int aoff1 = ((4 + lg) ^ rot) << 3;    // k-slice 1
  const int arow = (wm + lm) << 6;            // A frag row base (elements)
  const int brow = (wn + lm) << 6;            // B frag row base

  const int kbeg = (KSPLIT == 2) ? kh * (K >> 1) : 0;
  const int nk = ((KSPLIT == 2) ? (K >> 1) : K) >> 6;   // #K-tiles (>=2 for all uses)

  // staging: thread tid covers row rb=tid>>3 of a 64-row band, phys 16B slot tid&7;
  // global source column pre-swizzled so linear LDS dest yields swizzled layout.
  const int rb = tid >> 3;
  const int gcol = (((tid & 7) ^ (rb & 7)) << 3);
  const unsigned short* gA = A  + (size_t)(m0 + rb) * K + kbeg + gcol;
  const unsigned short* gB = Bt + (size_t)(n0 + rb) * K + kbeg + gcol;

  auto stage = [&](const unsigned short* g, int b, int st, unsigned short* seg) {
    async16(g + (size_t)b * 64 * K + (size_t)st * 64, seg + b * 4096 + tid * 8);
  };

  f32x4 acc[8][4] = {};

  // ---- prologue: K0 full (8 bands) + K1 first 6 bands; seal K0 with vmcnt(6) ----
  {
    unsigned short* A0s = lds;
    unsigned short* B0s = lds + 16384;
    unsigned short* A1s = lds + 32768;
    unsigned short* B1s = lds + 49152;
    stage(gA, 0, 0, A0s); stage(gA, 2, 0, A0s);
    stage(gB, 0, 0, B0s); stage(gB, 1, 0, B0s);
    stage(gA, 1, 0, A0s); stage(gA, 3, 0, A0s);
    stage(gB, 2, 0, B0s); stage(gB, 3, 0, B0s);
    stage(gA, 0, 1, A1s); stage(gA, 2, 1, A1s);
    stage(gB, 0, 1, B1s); stage(gB, 1, 1, B1s);
    stage(gA, 1, 1, A1s); stage(gA, 3, 1, A1s);
    __builtin_amdgcn_s_waitcnt(0x0F76);   // vmcnt(6): K0 landed, K1's 6 in flight
    __builtin_amdgcn_s_barrier();
  }

  for (int t = 0; t < nk; ++t) {
    const int cur = t & 1;
    unsigned short* LA = lds + (cur << 15);
    unsigned short* LB = LA + 16384;
    unsigned short* NA = lds + ((cur ^ 1) << 15);
    unsigned short* NB = NA + 16384;
    short8 af[4][2], bf[4][2];

    // ---------- phase 0: (m-half0, n-half0) ----------
    if (t + 1 < nk) { stage(gB, 2, t + 1, NB); stage(gB, 3, t + 1, NB); }
#pragma unroll
    for (int i = 0; i < 4; i++) {
      af[i][0] = *(const short8*)(LA + arow + i * 1024 + aoff0);
      af[i][1] = *(const short8*)(LA + arow + i * 1024 + aoff1);
    }
#pragma unroll
    for (int n = 0; n < 2; n++) {
      bf[n][0] = *(const short8*)(LB + brow + n * 1024 + aoff0);
      bf[n][1] = *(const short8*)(LB + brow + n * 1024 + aoff1);
    }
    __builtin_amdgcn_s_barrier();
    __builtin_amdgcn_s_setprio(1);
    MFMA_Q(0, 0);
    __builtin_amdgcn_s_setprio(0);
    __builtin_amdgcn_s_barrier();

    // ---------- phase 1: (m-half0, n-half1) ----------
    if (t + 2 < nk) { stage(gA, 0, t + 2, LA); stage(gA, 2, t + 2, LA); }
#pragma unroll
    for (int n = 2; n < 4; n++) {
      bf[n][0] = *(const short8*)(LB + brow + n * 1024 + aoff0);
      bf[n][1] = *(const short8*)(LB + brow + n * 1024 + aoff1);
    }
    __builtin_amdgcn_s_barrier();
    __builtin_amdgcn_s_setprio(1);
    MFMA_Q(0, 1);
    __builtin_amdgcn_s_setprio(0);
    __builtin_amdgcn_s_barrier();

    // ---------- phase 2: (m-half1, n-half1) ----------
    if (t + 2 < nk) { stage(gB, 0, t + 2, LB); stage(gB, 1, t + 2, LB); }
#pragma unroll
    for (int i = 0; i < 4; i++) {
      af[i][0] = *(const short8*)(LA + arow + 4096 + i * 1024 + aoff0);
      af[i][1] = *(const short8*)(LA + arow + 4096 + i * 1024 + aoff1);
    }
    __builtin_amdgcn_s_barrier();
    __builtin_amdgcn_s_setprio(1);
    MFMA_Q(1, 1);
    __builtin_amdgcn_s_setprio(0);
    __builtin_amdgcn_s_barrier();

    // ---------- phase 3: (m-half1, n-half0); seal next K-tile ----------
    if (t + 2 < nk) {
      stage(gA, 1, t + 2, LA); stage(gA, 3, t + 2, LA);
      __builtin_amdgcn_s_waitcnt(0x0F76);   // vmcnt(6): K-tile t+1 fully landed
    } else {
      __builtin_amdgcn_s_waitcnt(0x0F70);   // tail: vmcnt(0)
    }
    __builtin_amdgcn_s_barrier();
    __builtin_amdgcn_s_setprio(1);
    MFMA_Q(1, 0);
    __builtin_amdgcn_s_setprio(0);
    __builtin_amdgcn_s_barrier();
  }

  // ---- epilogue: C/D layout col=lane&15, row=(lane>>4)*4+r ----
  unsigned short* Cb = (unsigned short*)Cout + (KSPLIT == 2 ? (size_t)kh * M * N : 0);
#pragma unroll
  for (int nt = 0; nt < 4; nt++) {
    int col = n0 + wn + nt * 16 + lm;
    float bv = BIAS ? bias[col] : 0.0f;
#pragma unroll
    for (int mf = 0; mf < 8; mf++) {
#pragma unroll
      for (int r = 0; r < 4; r++) {
        int row = m0 + wm + mf * 16 + lg * 4 + r;
        float v = acc[mf][nt][r] + bv;
        if (RELU) v = fmaxf(v, 0.0f);
        if (OUT_BF16) Cb[(size_t)row * N + col] = f2bf(v);
        else          ((float*)Cout)[(size_t)row * N + col] = v;
      }
    }
  }
}

// ------------- attention: 128 q/block, 32 q/wave, 4 blocks/CU, reg-prefetch K/V -------------
// (round-1 structure, measured best) + raw v_exp_f32 softmax.
// S^T = K*Q^T; p = exp2(min(s',CLIP2)) via __builtin_amdgcn_exp2f; lower clip dropped
// (negligible vs rowsum); shift cancels in normalization. Rowsum via MFMA vs all-ones.
// Per-wave Ps roundtrip (lgkm wait only). LDS XOR swizzle phys_col = col ^ ((row&7)*8).
__global__ __launch_bounds__(256, 4) void attn_kernel(
    const unsigned short* __restrict__ QKV,   // [8192][3072]: q|k|v
    const unsigned short* __restrict__ Vt_g,  // [64 bh][64 dh][2048 kv]
    unsigned short* __restrict__ ctx) {       // [8192][1024]
  __shared__ __align__(16) unsigned short Ks[64 * 64];       // [kv][dh] swizzled
  __shared__ __align__(16) unsigned short Vs[64 * 64];       // [dh][kv] swizzled
  __shared__ __align__(16) unsigned short Ps[4 * 32 * 64];   // per-wave [q][kv] swizzled
  const int bh = blockIdx.x, b = bh >> 4, h = bh & 15;
  const int q0 = blockIdx.y * 128;
  const int tid = threadIdx.x, wave = tid >> 6, lane = tid & 63;
  const int lm = lane & 15, lq = lane >> 4;
  const int srow = tid >> 3, scol = (tid & 7) * 8;           // srow 0..31
  const int rot = (lm & 7) * 8;

  short8 qf[2][2];
#pragma unroll
  for (int ntq = 0; ntq < 2; ntq++) {
    const unsigned short* qp =
        QKV + (size_t)(b * SEQ + q0 + wave * 32 + ntq * 16 + lm) * 3072 + h * DH;
#pragma unroll
    for (int sl = 0; sl < 2; sl++) qf[ntq][sl] = *(const short8*)(qp + sl * 32 + lq * 8);
  }
  const short8 ones = {0x3F80, 0x3F80, 0x3F80, 0x3F80, 0x3F80, 0x3F80, 0x3F80, 0x3F80};
  f32x4 oacc[2][4] = {};
  f32x4 lsum[2] = {};

  const int sdst = srow * 64 + (scol ^ ((srow & 7) * 8));   // rows 0..31; +2048 for 32..63
  const unsigned short* kg = QKV + (size_t)(b * SEQ) * 3072 + D_MODEL + h * DH + scol;
  const unsigned short* vg = Vt_g + (size_t)(bh * DH + srow) * SEQ + scol;

  // prefetch tile 0
  uint4 kr0 = *(const uint4*)(kg + (size_t)srow * 3072);
  uint4 kr1 = *(const uint4*)(kg + (size_t)(srow + 32) * 3072);
  uint4 vr0 = *(const uint4*)(vg);
  uint4 vr1 = *(const uint4*)(vg + 32 * SEQ);

  for (int it = 0; it < SEQ / 64; it++) {
    *(uint4*)(Ks + sdst)        = kr0;
    *(uint4*)(Ks + sdst + 2048) = kr1;
    *(uint4*)(Vs + sdst)        = vr0;
    *(uint4*)(Vs + sdst + 2048) = vr1;
    __syncthreads();
    if (it + 1 < SEQ / 64) {   // prefetch next tile; overlaps the whole compute phase
      const int kvn = (it + 1) * 64;
      kr0 = *(const uint4*)(kg + (size_t)(kvn + srow) * 3072);
      kr1 = *(const uint4*)(kg + (size_t)(kvn + srow + 32) * 3072);
      vr0 = *(const uint4*)(vg + kvn);
      vr1 = *(const uint4*)(vg + 32 * SEQ + kvn);
    }

    // S^T = K * Q^T ; p = exp2(min(s',CLIP2)); truncation-pack to per-wave Ps
#pragma unroll
    for (int mt = 0; mt < 4; mt++) {
      const unsigned short* krow = Ks + (mt * 16 + lm) * 64;
      short8 kf0 = *(const short8*)(krow + ((lq * 8) ^ rot));
      short8 kf1 = *(const short8*)(krow + ((32 + lq * 8) ^ rot));
#pragma unroll
      for (int ntq = 0; ntq < 2; ntq++) {
        f32x4 sa = {0.f, 0.f, 0.f, 0.f};
        sa = __builtin_amdgcn_mfma_f32_16x16x32_bf16(kf0, qf[ntq][0], sa, 0, 0, 0);
        sa = __builtin_amdgcn_mfma_f32_16x16x32_bf16(kf1, qf[ntq][1], sa, 0, 0, 0);
        float p0 = hw_exp2(fminf(sa[0], CLIP2));
        float p1 = hw_exp2(fminf(sa[1], CLIP2));
        float p2 = hw_exp2(fminf(sa[2], CLIP2));
        float p3 = hw_exp2(fminf(sa[3], CLIP2));
        uint2 d;
        d.x = pack_trunc(p0, p1);
        d.y = pack_trunc(p2, p3);
        *(uint2*)(Ps + wave * 2048 + (ntq * 16 + lm) * 64 + ((mt * 16 + lq * 4) ^ rot)) = d;
      }
    }
    // wave-local LDS RAW: wait lgkmcnt(0) only (vmcnt=63, expcnt=7 -> 0xC07F)
    __builtin_amdgcn_s_waitcnt(0xC07F);
    short8 pf[2][2];
#pragma unroll
    for (int mq = 0; mq < 2; mq++)
#pragma unroll
      for (int sl = 0; sl < 2; sl++)
        pf[mq][sl] = *(const short8*)(Ps + wave * 2048 + (mq * 16 + lm) * 64 + ((sl * 32 + lq * 8) ^ rot));
#pragma unroll
    for (int nt = 0; nt < 4; nt++) {
      const unsigned short* vrow = Vs + (nt * 16 + lm) * 64;
      short8 vf0 = *(const short8*)(vrow + ((lq * 8) ^ rot));
      short8 vf1 = *(const short8*)(vrow + ((32 + lq * 8) ^ rot));
#pragma unroll
      for (int mq = 0; mq < 2; mq++) {
        oacc[mq][nt] = __builtin_amdgcn_mfma_f32_16x16x32_bf16(pf[mq][0], vf0, oacc[mq][nt], 0, 0, 0);
        oacc[mq][nt] = __builtin_amdgcn_mfma_f32_16x16x32_bf16(pf[mq][1], vf1, oacc[mq][nt], 0, 0, 0);
      }
    }
#pragma unroll
    for (int mq = 0; mq < 2; mq++) {
      lsum[mq] = __builtin_amdgcn_mfma_f32_16x16x32_bf16(pf[mq][0], ones, lsum[mq], 0, 0, 0);
      lsum[mq] = __builtin_amdgcn_mfma_f32_16x16x32_bf16(pf[mq][1], ones, lsum[mq], 0, 0, 0);
    }
    __syncthreads();   // all waves done reading Ks/Vs before next staging write
  }

#pragma unroll
  for (int mq = 0; mq < 2; mq++) {
    float linv[4];
#pragma unroll
    for (int r = 0; r < 4; r++) linv[r] = 1.0f / lsum[mq][r];
    const size_t rowbase =
        (size_t)(b * SEQ + q0 + wave * 32 + mq * 16 + lq * 4) * D_MODEL + h * DH;
#pragma unroll
    for (int nt = 0; nt < 4; nt++) {
#pragma unroll
      for (int r = 0; r < 4; r++) {
        ctx[rowbase + (size_t)r * D_MODEL + nt * 16 + lm] = f2bf(oacc[mq][nt][r] * linv[r]);
      }
    }
  }
}

// ------------- residual + layernorm -------------
// THREE=1: out = LN(A + bf16(B1) + bf16(B2) + cbias)  (split-K partial merge + bias)
template<int B_BF16, int WRITE_BF16, int THREE>
__global__ void ln_kernel(const float* __restrict__ A, const void* __restrict__ Bv,
                          const void* __restrict__ B2v, const float* __restrict__ cbias,
                          const float* __restrict__ gamma, const float* __restrict__ beta,
                          float* __restrict__ outf, unsigned short* __restrict__ outb) {
  const int row = blockIdx.x;
  const int tid = threadIdx.x;
  const size_t base = (size_t)row * D_MODEL + tid * 4;
  float4 xa = *(const float4*)(A + base);
  float4 xb;
  if (B_BF16) {
    ushort4 u = *(const ushort4*)((const unsigned short*)Bv + base);
    xb.x = bf2f(u.x); xb.y = bf2f(u.y); xb.z = bf2f(u.z); xb.w = bf2f(u.w);
  } else {
    xb = *(const float4*)((const float*)Bv + base);
  }
  if (THREE) {
    ushort4 u2 = *(const ushort4*)((const unsigned short*)B2v + base);
    float4 cb = *(const float4*)(cbias + tid * 4);
    xb.x += bf2f(u2.x) + cb.x; xb.y += bf2f(u2.y) + cb.y;
    xb.z += bf2f(u2.z) + cb.z; xb.w += bf2f(u2.w) + cb.w;
  }
  float v0 = xa.x + xb.x, v1 = xa.y + xb.y, v2 = xa.z + xb.z, v3 = xa.w + xb.w;
  float s = v0 + v1 + v2 + v3;
  float sq = v0 * v0 + v1 * v1 + v2 * v2 + v3 * v3;
#pragma unroll
  for (int off = 1; off < 64; off <<= 1) {
    s  += __shfl_xor(s, off);
    sq += __shfl_xor(sq, off);
  }
  __shared__ float red[8];
  int wave = tid >> 6;
  if ((tid & 63) == 0) { red[wave * 2] = s; red[wave * 2 + 1] = sq; }
  __syncthreads();
  s  = red[0] + red[2] + red[4] + red[6];
  sq = red[1] + red[3] + red[5] + red[7];
  float mean = s * (1.0f / D_MODEL);
  float var = sq * (1.0f / D_MODEL) - mean * mean;
  float inv = rsqrtf(var + 1e-8f);
  float4 g  = *(const float4*)(gamma + tid * 4);
  float4 be = *(const float4*)(beta + tid * 4);
  float o0 = (v0 - mean) * inv * g.x + be.x;
  float o1 = (v1 - mean) * inv * g.y + be.y;
  float o2 = (v2 - mean) * inv * g.z + be.z;
  float o3 = (v3 - mean) * inv * g.w + be.w;
  float4 of; of.x = o0; of.y = o1; of.z = o2; of.w = o3;
  *(float4*)(outf + base) = of;
  if (WRITE_BF16) {
    ushort4 ub; ub.x = f2bf(o0); ub.y = f2bf(o1); ub.z = f2bf(o2); ub.w = f2bf(o3);
    *(ushort4*)(outb + base) = ub;
  }
}

extern "C" void kernel_launch(void* const* d_in, const int* in_sizes, int n_in,
                              void* d_out, int out_size, void* d_ws, size_t ws_size,
                              hipStream_t stream) {
  const float* x     = (const float*)d_in[0];
  const float* wq    = (const float*)d_in[1];
  const float* bq    = (const float*)d_in[2];
  const float* wk    = (const float*)d_in[3];
  const float* bk    = (const float*)d_in[4];
  const float* wv    = (const float*)d_in[5];
  const float* bv    = (const float*)d_in[6];
  const float* wo    = (const float*)d_in[7];
  const float* bo    = (const float*)d_in[8];
  const float* w1    = (const float*)d_in[9];
  const float* b1    = (const float*)d_in[10];
  const float* w2    = (const float*)d_in[11];
  const float* b2    = (const float*)d_in[12];
  const float* gamma = (const float*)d_in[13];
  const float* beta  = (const float*)d_in[14];

  char* ws = (char*)d_ws;
  const size_t MB = 1ull << 20;
  // buffer plan — phase-aliased (stream order guarantees no overlap-in-time):
  //   [0,16)   xb (cast->QKV)  /  out1b (LN1->FFN1)
  //   [0,32)   ffn2 partials (FFN2->LN2)
  //   [16,22)  wqkvT  [22,24) woT  [24,32) w1T  [32,40) w2T  [40,41) bqkv
  //   [41,89)  qkvb (QKV->attn) / oprojp 32MB@41 (outproj->LN1) / h1@[41,105) (FFN1->FFN2)
  //   [89,105) Vt_g (->attn)
  //   [105,121) ctx (attn->outproj)
  //   [121,153) out1f (LN1->LN2)
  unsigned short* xb      = (unsigned short*)(ws + 0 * MB);
  unsigned short* out1b   = (unsigned short*)(ws + 0 * MB);
  unsigned short* ffn2    = (unsigned short*)(ws + 0 * MB);    // 32 MB: two bf16 partials
  unsigned short* wqkvT   = (unsigned short*)(ws + 16 * MB);
  unsigned short* woT     = (unsigned short*)(ws + 22 * MB);
  unsigned short* w1T     = (unsigned short*)(ws + 24 * MB);
  unsigned short* w2T     = (unsigned short*)(ws + 32 * MB);
  float*          bqkv    = (float*)(ws + 40 * MB);
  unsigned short* qkvb    = (unsigned short*)(ws + 41 * MB);
  unsigned short* oprojp  = (unsigned short*)(ws + 41 * MB);   // 32 MB: two bf16 partials
  unsigned short* h1      = (unsigned short*)(ws + 41 * MB);
  unsigned short* Vt_g    = (unsigned short*)(ws + 89 * MB);
  unsigned short* ctx     = (unsigned short*)(ws + 105 * MB);
  float*          out1f   = (float*)(ws + 121 * MB);

  // preprocessing
  cast_kernel<<<(MTOT * D_MODEL / 4 + 255) / 256, 256, 0, stream>>>(x, xb, MTOT * D_MODEL / 4);
  transpose_weights_kernel<<<3072, 256, 0, stream>>>(
      wq, wk, wv, wo, w1, w2, wqkvT, woT, w1T, w2T);
  bias_concat_kernel<<<12, 256, 0, stream>>>(bq, bk, bv, bqkv);

  // fused QKV projection: [8192][3072] — 256^2 8-phase kernel (384 wg, %8==0)
  gemm256_bt_kernel<0, 1, 1, 1><<<(3072 / 256) * (MTOT / 256), 512, 0, stream>>>(
      xb, wqkvT, bqkv, qkvb, MTOT, 3072, D_MODEL);
  // V -> Vt_g[bh][dh][kv]
  transpose_v_kernel<<<dim3(SEQ / 32, DH / 32, BATCH * NHEAD), 256, 0, stream>>>(qkvb, Vt_g);
  // attention: 128 q/block, 32 q/wave; grid.x = bh (q-blocks of one bh share an XCD's L2)
  attn_kernel<<<dim3(BATCH * NHEAD, SEQ / 128), 256, 0, stream>>>(qkvb, Vt_g, ctx);

  // out-proj: 256^2 split-K=2 (256 wg = exact 1 round); partials + bo merged in LN1
  gemm256_bt_kernel<0, 1, 2, 0><<<2 * (D_MODEL / 256) * (MTOT / 256), 512, 0, stream>>>(
      ctx, woT, nullptr, oprojp, MTOT, D_MODEL, D_MODEL);
  ln_kernel<1, 1, 1><<<MTOT, 256, 0, stream>>>(
      x, oprojp, oprojp + (size_t)MTOT * D_MODEL, bo, gamma, beta, out1f, out1b);
  // FFN1: 256^2 8-phase (512 wg = exactly 2 rounds at 1 block/CU)
  gemm256_bt_kernel<1, 1, 1, 1><<<(DFF / 256) * (MTOT / 256), 512, 0, stream>>>(
      out1b, w1T, b1, h1, MTOT, DFF, D_MODEL);
  // FFN2 split-K=2: 256 wg (exactly 1/CU), bf16 partials; bias b2 folded into LN2
  gemm256_bt_kernel<0, 1, 2, 0><<<2 * (D_MODEL / 256) * (MTOT / 256), 512, 0, stream>>>(
      h1, w2T, nullptr, ffn2, MTOT, D_MODEL, DFF);
  ln_kernel<1, 0, 1><<<MTOT, 256, 0, stream>>>(
      out1f, ffn2, ffn2 + (size_t)MTOT * D_MODEL, b2, gamma, beta, (float*)d_out, nullptr);
}